// Round 2
// baseline (537.565 us; speedup 1.0000x reference)
//
#include <hip/hip_runtime.h>

#define DIM 256
#define SCAN_B 256

typedef __attribute__((ext_vector_type(8))) short short8;
typedef __attribute__((ext_vector_type(8))) unsigned short u16x8;
typedef __attribute__((ext_vector_type(4))) float f32x4;

__device__ __forceinline__ unsigned short f32_to_bf16(float x) {
    unsigned int u = __float_as_uint(x);
    unsigned int r = u + 0x7FFFu + ((u >> 16) & 1u);
    return (unsigned short)(r >> 16);
}
__device__ __forceinline__ float bf16_to_f32(unsigned short h) {
    return __uint_as_float(((unsigned int)h) << 16);
}

// ---------------- degree histogram ----------------
__global__ void deg_kernel(const int* __restrict__ dst, int E, int* __restrict__ deg) {
    int e = blockIdx.x * blockDim.x + threadIdx.x;
    if (e < E) atomicAdd(&deg[dst[e]], 1);
}

// ---------------- hierarchical exclusive scan (deg -> row_start) ----------------
__global__ void scan1_kernel(const int* __restrict__ deg, int N,
                             int* __restrict__ excl, int* __restrict__ bsums) {
    __shared__ int s[SCAN_B];
    int tid = threadIdx.x;
    int i = blockIdx.x * SCAN_B + tid;
    int v = (i < N) ? deg[i] : 0;
    s[tid] = v;
    __syncthreads();
    #pragma unroll
    for (int off = 1; off < SCAN_B; off <<= 1) {
        int t = (tid >= off) ? s[tid - off] : 0;
        __syncthreads();
        s[tid] += t;
        __syncthreads();
    }
    if (i <= N) excl[i] = s[tid] - v;
    if (tid == SCAN_B - 1) bsums[blockIdx.x] = s[tid];
}

__global__ void scan2_kernel(int* __restrict__ bsums, int nb) {
    __shared__ int s[SCAN_B];
    int tid = threadIdx.x;
    int v = (tid < nb) ? bsums[tid] : 0;
    s[tid] = v;
    __syncthreads();
    #pragma unroll
    for (int off = 1; off < SCAN_B; off <<= 1) {
        int t = (tid >= off) ? s[tid - off] : 0;
        __syncthreads();
        s[tid] += t;
        __syncthreads();
    }
    if (tid < nb) bsums[tid] = s[tid] - v;
}

// scan3 + inv_deg fused
__global__ void scan3_kernel(const int* __restrict__ excl, const int* __restrict__ bsums,
                             const int* __restrict__ deg, int N,
                             int* __restrict__ row_start, float* __restrict__ inv_deg) {
    int i = blockIdx.x * SCAN_B + threadIdx.x;
    if (i <= N) row_start[i] = excl[i] + bsums[blockIdx.x];
    if (i < N) inv_deg[i] = 1.0f / (float)max(deg[i], 1);
}

// ---------------- CSR bucket fill ----------------
__global__ void fill_kernel(const int* __restrict__ src, const int* __restrict__ dst, int E,
                            const int* __restrict__ row_start, int* __restrict__ cursor,
                            int* __restrict__ csr_src) {
    int e = blockIdx.x * blockDim.x + threadIdx.x;
    if (e < E) {
        int d = dst[e];
        int pos = row_start[d] + atomicAdd(&cursor[d], 1);
        csr_src[pos] = src[e];
    }
}

// ---------------- combined prep: W -> bf16 transpose, x0 -> bf16 ----------------
__global__ void prep_kernel(const float* __restrict__ W, unsigned short* __restrict__ Wt,
                            const float* __restrict__ x0, unsigned short* __restrict__ x0b,
                            int n4) {
    int b = blockIdx.x;
    if (b < DIM) {
        int k = b, n = threadIdx.x;
        Wt[n * DIM + k] = f32_to_bf16(W[k * DIM + n]);
    } else {
        int i = (b - DIM) * 256 + threadIdx.x;
        if (i < n4) {
            float4 v = ((const float4*)x0)[i];
            ushort4 o;
            o.x = f32_to_bf16(v.x); o.y = f32_to_bf16(v.y);
            o.z = f32_to_bf16(v.z); o.w = f32_to_bf16(v.w);
            ((ushort4*)x0b)[i] = o;
        }
    }
}

// ================= fused layer: aggregate (gather+mix) -> LDS -> MFMA GEMM =======
// One block = 64 output rows x 256 cols. Phase 1: wave w aggregates nodes
// [m0+16w, m0+16w+16) into hs (bf16, 16B-chunk XOR-swizzled: chunk ^= row&7 so the
// 512B-row tile spreads fragment reads across all 8 bank groups). Phase 2: no-barrier
// K-loop: A-frags from hs (ds_read_b128), B-frags straight from L2-resident Wt into
// registers (no LDS staging, no vmcnt drains). Single __syncthreads in the kernel.
template <bool LAST>
__global__ __launch_bounds__(256, 3) void layer_kernel(
    const unsigned short* __restrict__ xh, const unsigned short* __restrict__ x0b,
    const unsigned short* __restrict__ Wt,
    const int* __restrict__ row_start, const int* __restrict__ csr_src,
    const float* __restrict__ inv_deg,
    float* __restrict__ out_f32, unsigned short* __restrict__ out_bf16, int N)
{
    __shared__ unsigned short hs[64 * 256];   // 32 KB

    const int t    = threadIdx.x;
    const int w    = t >> 6;
    const int lane = t & 63;
    const int m0   = blockIdx.x * 64;

    // ---------------- phase 1: aggregate + residual mix -> hs ----------------
    {
        const int half = lane >> 5;
        const int ck   = lane & 31;            // 16B chunk index
        const int c    = ck * 8;               // column base (shorts)
        for (int i = 0; i < 16; i++) {
            const int lrow = w * 16 + i;
            const int node = m0 + lrow;
            unsigned short* dst = &hs[lrow * 256 + (ck ^ (lrow & 7)) * 8];
            if (node < N) {
                const int beg = row_start[node];
                const int end = row_start[node + 1];
                const float dscale = 0.9f * inv_deg[node];
                const u16x8 xv = *(const u16x8*)(x0b + (size_t)node * DIM + c);
                float a[8];
                #pragma unroll
                for (int j = 0; j < 8; j++) a[j] = 0.f;
                int e = beg;
                for (; e + 4 <= end; e += 4) {           // 4 edges/iter (2 per half)
                    int s0 = csr_src[e + half];
                    int s1 = csr_src[e + 2 + half];
                    u16x8 v0 = *(const u16x8*)(xh + (size_t)s0 * DIM + c);
                    u16x8 v1 = *(const u16x8*)(xh + (size_t)s1 * DIM + c);
                    #pragma unroll
                    for (int j = 0; j < 8; j++) a[j] += bf16_to_f32(v0[j]) + bf16_to_f32(v1[j]);
                }
                if (e + 2 <= end) {
                    int s0 = csr_src[e + half];
                    u16x8 v0 = *(const u16x8*)(xh + (size_t)s0 * DIM + c);
                    #pragma unroll
                    for (int j = 0; j < 8; j++) a[j] += bf16_to_f32(v0[j]);
                    e += 2;
                }
                if (e < end && half == 0) {
                    int s0 = csr_src[e];
                    u16x8 v0 = *(const u16x8*)(xh + (size_t)s0 * DIM + c);
                    #pragma unroll
                    for (int j = 0; j < 8; j++) a[j] += bf16_to_f32(v0[j]);
                }
                #pragma unroll
                for (int j = 0; j < 8; j++) a[j] += __shfl_xor(a[j], 32);
                if (half == 0) {
                    u16x8 o;
                    #pragma unroll
                    for (int j = 0; j < 8; j++)
                        o[j] = f32_to_bf16(0.1f * bf16_to_f32(xv[j]) + dscale * a[j]);
                    *(u16x8*)dst = o;
                }
            } else if (half == 0) {
                u16x8 z;
                #pragma unroll
                for (int j = 0; j < 8; j++) z[j] = 0;
                *(u16x8*)dst = z;               // zero pad rows: GEMM reads them
            }
        }
    }
    __syncthreads();   // hs complete (also drains LDS writes)

    // ---------------- phase 2: out = relu(hs @ W), barrier-free K-loop ----------
    const int lm = lane & 15, q = lane >> 4;
    f32x4 acc[4][4];
    #pragma unroll
    for (int mi = 0; mi < 4; mi++)
        #pragma unroll
        for (int ni = 0; ni < 4; ni++)
            acc[mi][ni] = (f32x4){0.f, 0.f, 0.f, 0.f};

    #pragma unroll
    for (int ks = 0; ks < 8; ks++) {
        short8 a[4];
        #pragma unroll
        for (int mi = 0; mi < 4; mi++) {
            int row = mi * 16 + lm;
            int ch = (ks * 4 + q) ^ (row & 7);
            a[mi] = *(const short8*)&hs[row * 256 + ch * 8];
        }
        #pragma unroll
        for (int ni = 0; ni < 4; ni++) {
            int brow = w * 64 + ni * 16 + lm;
            short8 b = *(const short8*)(Wt + (size_t)brow * DIM + ks * 32 + q * 8);
            #pragma unroll
            for (int mi = 0; mi < 4; mi++)
                acc[mi][ni] = __builtin_amdgcn_mfma_f32_16x16x32_bf16(a[mi], b, acc[mi][ni], 0, 0, 0);
        }
    }

    #pragma unroll
    for (int mi = 0; mi < 4; mi++) {
        const int rowb = m0 + mi * 16 + q * 4;
        #pragma unroll
        for (int ni = 0; ni < 4; ni++) {
            const int col = w * 64 + ni * 16 + lm;
            #pragma unroll
            for (int r = 0; r < 4; r++) {
                int row = rowb + r;
                if (row < N) {
                    float v = fmaxf(acc[mi][ni][r], 0.0f);
                    if (LAST) out_f32[(size_t)row * DIM + col] = v;
                    else      out_bf16[(size_t)row * DIM + col] = f32_to_bf16(v);
                }
            }
        }
    }
}

extern "C" void kernel_launch(void* const* d_in, const int* in_sizes, int n_in,
                              void* d_out, int out_size, void* d_ws, size_t ws_size,
                              hipStream_t stream) {
    const float* x0  = (const float*)d_in[0];
    const int*   ei  = (const int*)d_in[1];
    const float* W   = (const float*)d_in[2];
    float*       out = (float*)d_out;

    const int N = in_sizes[0] / DIM;
    const int E = in_sizes[1] / 2;
    const int N_pad = (N + 127) & ~127;
    const int* src = ei;
    const int* dst = ei + E;

    const int nb = (N + 1 + SCAN_B - 1) / SCAN_B;

    char* ws = (char*)d_ws;
    size_t off = 0;
    auto alloc = [&](size_t bytes) { char* p = ws + off; off += (bytes + 15) & ~size_t(15); return p; };
    unsigned short* act0    = (unsigned short*)alloc((size_t)N_pad * DIM * 2);
    unsigned short* act1    = (unsigned short*)alloc((size_t)N_pad * DIM * 2);
    unsigned short* x0b     = (unsigned short*)alloc((size_t)N_pad * DIM * 2);
    unsigned short* Wt      = (unsigned short*)alloc((size_t)DIM * DIM * 2);
    float* inv_deg  = (float*)alloc((size_t)N * 4);
    int*   deg      = (int*)  alloc((size_t)N * 4 * 2);   // deg + cursor, adjacent
    int*   cursor   = deg + N;
    int*   row_start= (int*)  alloc((size_t)(N + 1) * 4);
    int*   excl     = (int*)  alloc((size_t)(N + 1) * 4);
    int*   bsums    = (int*)  alloc((size_t)nb * 4);
    int*   csr_src  = (int*)  alloc((size_t)E * 4);

    // ---- CSR build + W/x0 prep (per launch) ----
    hipMemsetAsync(deg, 0, (size_t)N * 4 * 2, stream);   // deg + cursor in one shot
    deg_kernel<<<(E + 255) / 256, 256, 0, stream>>>(dst, E, deg);
    scan1_kernel<<<nb, SCAN_B, 0, stream>>>(deg, N, excl, bsums);
    scan2_kernel<<<1, SCAN_B, 0, stream>>>(bsums, nb);
    scan3_kernel<<<nb, SCAN_B, 0, stream>>>(excl, bsums, deg, N, row_start, inv_deg);
    fill_kernel<<<(E + 255) / 256, 256, 0, stream>>>(src, dst, E, row_start, cursor, csr_src);
    const int n4 = N * DIM / 4;
    prep_kernel<<<DIM + (n4 + 255) / 256, 256, 0, stream>>>(W, Wt, x0, x0b, n4);

    // ---- 5 fused GCN layers (gather src ping-pongs; residual always x0b) ----
    const int nb64 = (N + 63) / 64;
    const unsigned short* gsrc = x0b;
    unsigned short* gdst = act0;
    for (int layer = 0; layer < 5; layer++) {
        if (layer == 4)
            layer_kernel<true><<<nb64, 256, 0, stream>>>(gsrc, x0b, Wt, row_start, csr_src,
                                                         inv_deg, out, nullptr, N);
        else
            layer_kernel<false><<<nb64, 256, 0, stream>>>(gsrc, x0b, Wt, row_start, csr_src,
                                                          inv_deg, nullptr, gdst, N);
        gsrc = gdst;
        gdst = (gdst == act0) ? act1 : act0;
    }
}

// Round 3
// 452.547 us; speedup vs baseline: 1.1879x; 1.1879x over previous
//
#include <hip/hip_runtime.h>

#define DIM 256
#define SCAN_B 256

typedef __attribute__((ext_vector_type(8))) short short8;
typedef __attribute__((ext_vector_type(8))) unsigned short u16x8;
typedef __attribute__((ext_vector_type(4))) float f32x4;

__device__ __forceinline__ unsigned short f32_to_bf16(float x) {
    unsigned int u = __float_as_uint(x);
    unsigned int r = u + 0x7FFFu + ((u >> 16) & 1u);
    return (unsigned short)(r >> 16);
}
__device__ __forceinline__ float bf16_to_f32(unsigned short h) {
    return __uint_as_float(((unsigned int)h) << 16);
}

// ---------------- fused: degree histogram + W->bf16 transpose + x0->bf16 --------
// independent work split by block range (saves one launch + gap)
__global__ void degprep_kernel(const int* __restrict__ dst, int E, int* __restrict__ deg,
                               const float* __restrict__ W, unsigned short* __restrict__ Wt,
                               const float* __restrict__ x0, unsigned short* __restrict__ x0b,
                               int n4, int nbdeg) {
    int b = blockIdx.x;
    if (b < nbdeg) {
        int e = b * 256 + threadIdx.x;
        if (e < E) atomicAdd(&deg[dst[e]], 1);
    } else if (b < nbdeg + DIM) {
        int k = b - nbdeg, n = threadIdx.x;
        Wt[n * DIM + k] = f32_to_bf16(W[k * DIM + n]);
    } else {
        int i = (b - nbdeg - DIM) * 256 + threadIdx.x;
        if (i < n4) {
            float4 v = ((const float4*)x0)[i];
            ushort4 o;
            o.x = f32_to_bf16(v.x); o.y = f32_to_bf16(v.y);
            o.z = f32_to_bf16(v.z); o.w = f32_to_bf16(v.w);
            ((ushort4*)x0b)[i] = o;
        }
    }
}

// ---------------- hierarchical exclusive scan (deg -> row_start) ----------------
__global__ void scan1_kernel(const int* __restrict__ deg, int N,
                             int* __restrict__ excl, int* __restrict__ bsums) {
    __shared__ int s[SCAN_B];
    int tid = threadIdx.x;
    int i = blockIdx.x * SCAN_B + tid;
    int v = (i < N) ? deg[i] : 0;
    s[tid] = v;
    __syncthreads();
    #pragma unroll
    for (int off = 1; off < SCAN_B; off <<= 1) {
        int t = (tid >= off) ? s[tid - off] : 0;
        __syncthreads();
        s[tid] += t;
        __syncthreads();
    }
    if (i <= N) excl[i] = s[tid] - v;
    if (tid == SCAN_B - 1) bsums[blockIdx.x] = s[tid];
}

__global__ void scan2_kernel(int* __restrict__ bsums, int nb) {
    __shared__ int s[SCAN_B];
    int tid = threadIdx.x;
    int v = (tid < nb) ? bsums[tid] : 0;
    s[tid] = v;
    __syncthreads();
    #pragma unroll
    for (int off = 1; off < SCAN_B; off <<= 1) {
        int t = (tid >= off) ? s[tid - off] : 0;
        __syncthreads();
        s[tid] += t;
        __syncthreads();
    }
    if (tid < nb) bsums[tid] = s[tid] - v;
}

// scan3 + inv_deg fused
__global__ void scan3_kernel(const int* __restrict__ excl, const int* __restrict__ bsums,
                             const int* __restrict__ deg, int N,
                             int* __restrict__ row_start, float* __restrict__ inv_deg) {
    int i = blockIdx.x * SCAN_B + threadIdx.x;
    if (i <= N) row_start[i] = excl[i] + bsums[blockIdx.x];
    if (i < N) inv_deg[i] = 1.0f / (float)max(deg[i], 1);
}

// ---------------- CSR bucket fill ----------------
__global__ void fill_kernel(const int* __restrict__ src, const int* __restrict__ dst, int E,
                            const int* __restrict__ row_start, int* __restrict__ cursor,
                            int* __restrict__ csr_src) {
    int e = blockIdx.x * blockDim.x + threadIdx.x;
    if (e < E) {
        int d = dst[e];
        int pos = row_start[d] + atomicAdd(&cursor[d], 1);
        csr_src[pos] = src[e];
    }
}

// ---------------- gather aggregation v2: half-wave per node, 4 edges in flight ----
// lanes 0-31 own node A, lanes 32-63 own node B (each half holds the full 256-col
// row: 32 lanes x 8 cols). 4 independent row-loads in flight per half per round ->
// rounds/node ~ ceil(deg/4). No cross-half combine needed.
__global__ __launch_bounds__(256) void aggregate_kernel(
    const unsigned short* __restrict__ xh, const unsigned short* __restrict__ x0b,
    const int* __restrict__ row_start, const int* __restrict__ csr_src,
    const float* __restrict__ inv_deg,
    unsigned short* __restrict__ h, int N)
{
    const int lane = threadIdx.x & 63;
    const int half = lane >> 5;
    const int node = blockIdx.x * 8 + ((threadIdx.x >> 6) << 1) + half;
    const int c    = (lane & 31) * 8;   // 8-column base within the row

    int beg = 0, end = 0;
    float dscale = 0.f;
    u16x8 xv;
    #pragma unroll
    for (int j = 0; j < 8; j++) xv[j] = 0;
    if (node < N) {
        beg = row_start[node];
        end = row_start[node + 1];
        dscale = 0.9f * inv_deg[node];                       // hoisted: hides latency
        xv = *(const u16x8*)(x0b + (size_t)node * DIM + c);  // under the edge loop
    }

    float a[8];
    #pragma unroll
    for (int j = 0; j < 8; j++) a[j] = 0.f;

    int e = beg;
    for (; e + 4 <= end; e += 4) {
        int s0 = csr_src[e], s1 = csr_src[e + 1], s2 = csr_src[e + 2], s3 = csr_src[e + 3];
        u16x8 v0 = *(const u16x8*)(xh + (size_t)s0 * DIM + c);
        u16x8 v1 = *(const u16x8*)(xh + (size_t)s1 * DIM + c);
        u16x8 v2 = *(const u16x8*)(xh + (size_t)s2 * DIM + c);
        u16x8 v3 = *(const u16x8*)(xh + (size_t)s3 * DIM + c);
        #pragma unroll
        for (int j = 0; j < 8; j++)
            a[j] += (bf16_to_f32(v0[j]) + bf16_to_f32(v1[j]))
                  + (bf16_to_f32(v2[j]) + bf16_to_f32(v3[j]));
    }
    if (e + 2 <= end) {
        int s0 = csr_src[e], s1 = csr_src[e + 1];
        u16x8 v0 = *(const u16x8*)(xh + (size_t)s0 * DIM + c);
        u16x8 v1 = *(const u16x8*)(xh + (size_t)s1 * DIM + c);
        #pragma unroll
        for (int j = 0; j < 8; j++)
            a[j] += bf16_to_f32(v0[j]) + bf16_to_f32(v1[j]);
        e += 2;
    }
    if (e < end) {
        int s0 = csr_src[e];
        u16x8 v0 = *(const u16x8*)(xh + (size_t)s0 * DIM + c);
        #pragma unroll
        for (int j = 0; j < 8; j++) a[j] += bf16_to_f32(v0[j]);
    }

    if (node < N) {
        u16x8 o;
        #pragma unroll
        for (int j = 0; j < 8; j++)
            o[j] = f32_to_bf16(0.1f * bf16_to_f32(xv[j]) + dscale * a[j]);
        *(u16x8*)(h + (size_t)node * DIM + c) = o;
    }
}

// ---------------- GEMM v3: zero-LDS, zero-barrier, all-register ----------------
// Skinny GEMM (K=256 -> 8 steps): staging+barriers dominated the LDS version, so
// A and B fragments are loaded straight from global (L2/L3-resident) into regs.
// Fully unrolled K-loop = pure {global_load x8, mfma x16} straight-line code the
// compiler can software-pipeline end to end. Fragment data identical to the
// r1-verified LDS path (A: lane(lm,q) holds h[row=lm][k=q*8..+8]; B likewise on Wt).
template <bool LAST>
__global__ __launch_bounds__(256) void gemm_kernel(
    const unsigned short* __restrict__ h, const unsigned short* __restrict__ Wt,
    float* __restrict__ out_f32, unsigned short* __restrict__ out_bf16, int N)
{
    const int t    = threadIdx.x;
    const int w    = t >> 6;
    const int lane = t & 63;
    const int lm   = lane & 15;
    const int q    = lane >> 4;
    const int wm   = w >> 1, wn = w & 1;
    const int m0   = blockIdx.x * 128;
    const int n0   = blockIdx.y * 128;

    const unsigned short* Ab = h  + (size_t)(m0 + wm * 64 + lm) * DIM + q * 8;
    const unsigned short* Bb = Wt + (size_t)(n0 + wn * 64 + lm) * DIM + q * 8;

    f32x4 acc[4][4];
    #pragma unroll
    for (int mi = 0; mi < 4; mi++)
        #pragma unroll
        for (int ni = 0; ni < 4; ni++)
            acc[mi][ni] = (f32x4){0.f, 0.f, 0.f, 0.f};

    #pragma unroll
    for (int ks = 0; ks < 8; ks++) {
        short8 a[4], b[4];
        #pragma unroll
        for (int mi = 0; mi < 4; mi++)
            a[mi] = *(const short8*)(Ab + (size_t)mi * 16 * DIM + ks * 32);
        #pragma unroll
        for (int ni = 0; ni < 4; ni++)
            b[ni] = *(const short8*)(Bb + (size_t)ni * 16 * DIM + ks * 32);
        #pragma unroll
        for (int ni = 0; ni < 4; ni++)
            #pragma unroll
            for (int mi = 0; mi < 4; mi++)
                acc[mi][ni] = __builtin_amdgcn_mfma_f32_16x16x32_bf16(a[mi], b[ni], acc[mi][ni], 0, 0, 0);
    }

    #pragma unroll
    for (int mi = 0; mi < 4; mi++) {
        const int rowb = m0 + wm * 64 + mi * 16 + q * 4;
        #pragma unroll
        for (int ni = 0; ni < 4; ni++) {
            const int col = n0 + wn * 64 + ni * 16 + lm;
            #pragma unroll
            for (int r = 0; r < 4; r++) {
                int row = rowb + r;
                if (row < N) {
                    float v = fmaxf(acc[mi][ni][r], 0.0f);
                    if (LAST) out_f32[(size_t)row * DIM + col] = v;
                    else      out_bf16[(size_t)row * DIM + col] = f32_to_bf16(v);
                }
            }
        }
    }
}

extern "C" void kernel_launch(void* const* d_in, const int* in_sizes, int n_in,
                              void* d_out, int out_size, void* d_ws, size_t ws_size,
                              hipStream_t stream) {
    const float* x0  = (const float*)d_in[0];
    const int*   ei  = (const int*)d_in[1];
    const float* W   = (const float*)d_in[2];
    float*       out = (float*)d_out;

    const int N = in_sizes[0] / DIM;
    const int E = in_sizes[1] / 2;
    const int N_pad = (N + 127) & ~127;
    const int* src = ei;
    const int* dst = ei + E;

    const int nb = (N + 1 + SCAN_B - 1) / SCAN_B;

    char* ws = (char*)d_ws;
    size_t off = 0;
    auto alloc = [&](size_t bytes) { char* p = ws + off; off += (bytes + 15) & ~size_t(15); return p; };
    unsigned short* h       = (unsigned short*)alloc((size_t)N_pad * DIM * 2);
    unsigned short* act     = (unsigned short*)alloc((size_t)N_pad * DIM * 2);
    unsigned short* x0b     = (unsigned short*)alloc((size_t)N_pad * DIM * 2);
    unsigned short* Wt      = (unsigned short*)alloc((size_t)DIM * DIM * 2);
    float* inv_deg  = (float*)alloc((size_t)N * 4);
    int*   deg      = (int*)  alloc((size_t)N * 4 * 2);   // deg + cursor, adjacent
    int*   cursor   = deg + N;
    int*   row_start= (int*)  alloc((size_t)(N + 1) * 4);
    int*   excl     = (int*)  alloc((size_t)(N + 1) * 4);
    int*   bsums    = (int*)  alloc((size_t)nb * 4);
    int*   csr_src  = (int*)  alloc((size_t)E * 4);

    // ---- CSR build + W/x0 prep (per launch) ----
    const int nbdeg = (E + 255) / 256;
    const int n4 = N * DIM / 4;
    hipMemsetAsync(deg, 0, (size_t)N * 4 * 2, stream);   // deg + cursor in one shot
    degprep_kernel<<<nbdeg + DIM + (n4 + 255) / 256, 256, 0, stream>>>(
        dst, E, deg, W, Wt, x0, x0b, n4, nbdeg);
    scan1_kernel<<<nb, SCAN_B, 0, stream>>>(deg, N, excl, bsums);
    scan2_kernel<<<1, SCAN_B, 0, stream>>>(bsums, nb);
    scan3_kernel<<<nb, SCAN_B, 0, stream>>>(excl, bsums, deg, N, row_start, inv_deg);
    fill_kernel<<<(E + 255) / 256, 256, 0, stream>>>(src, dst, E, row_start, cursor, csr_src);

    // ---- 5 GCN layers (layer 0 gathers from x0b; then act) ----
    dim3 ggrid(N_pad / 128, 2);
    for (int layer = 0; layer < 5; layer++) {
        const unsigned short* gsrc = (layer == 0) ? x0b : act;
        aggregate_kernel<<<(N + 7) / 8, 256, 0, stream>>>(gsrc, x0b, row_start, csr_src,
                                                          inv_deg, h, N);
        if (layer == 4)
            gemm_kernel<true><<<ggrid, 256, 0, stream>>>(h, Wt, out, nullptr, N);
        else
            gemm_kernel<false><<<ggrid, 256, 0, stream>>>(h, Wt, nullptr, act, N);
    }
}

// Round 4
// 362.638 us; speedup vs baseline: 1.4824x; 1.2479x over previous
//
#include <hip/hip_runtime.h>

#define DIM 256
#define ELL_W 32

typedef __attribute__((ext_vector_type(8))) short short8;
typedef __attribute__((ext_vector_type(8))) unsigned short u16x8;
typedef __attribute__((ext_vector_type(4))) float f32x4;

__device__ __forceinline__ unsigned short f32_to_bf16(float x) {
    unsigned int u = __float_as_uint(x);
    unsigned int r = u + 0x7FFFu + ((u >> 16) & 1u);
    return (unsigned short)(r >> 16);
}
__device__ __forceinline__ float bf16_to_f32(unsigned short h) {
    return __uint_as_float(((unsigned int)h) << 16);
}

__device__ __forceinline__ void load_lds16(const void* g, void* l) {
    __builtin_amdgcn_global_load_lds(
        (const __attribute__((address_space(1))) unsigned int*)g,
        (__attribute__((address_space(3))) unsigned int*)l, 16, 0, 0);
}

// ---- fused prep: ELL fill (atomic cursor; cursor ends as degree) + W->bf16
// transpose + x0->bf16 cast. Independent work split by block range. ----
__global__ void fillprep_kernel(const int* __restrict__ src, const int* __restrict__ dst,
                                int E, int* __restrict__ cursor, int* __restrict__ ell,
                                const float* __restrict__ W, unsigned short* __restrict__ Wt,
                                const float* __restrict__ x0, unsigned short* __restrict__ x0b,
                                int n4, int nbE) {
    int b = blockIdx.x;
    if (b < nbE) {
        int e = b * 256 + threadIdx.x;
        if (e < E) {
            int d = dst[e];
            int pos = atomicAdd(&cursor[d], 1);
            if (pos < ELL_W) ell[d * ELL_W + pos] = src[e];   // clamp: mem safety
        }
    } else if (b < nbE + DIM) {
        int k = b - nbE, n = threadIdx.x;
        Wt[n * DIM + k] = f32_to_bf16(W[k * DIM + n]);
    } else {
        int i = (b - nbE - DIM) * 256 + threadIdx.x;
        if (i < n4) {
            float4 v = ((const float4*)x0)[i];
            ushort4 o;
            o.x = f32_to_bf16(v.x); o.y = f32_to_bf16(v.y);
            o.z = f32_to_bf16(v.z); o.w = f32_to_bf16(v.w);
            ((ushort4*)x0b)[i] = o;
        }
    }
}

// ---------------- gather aggregation (r1-verified v1 structure, ELL-indexed) ----
// one 64-lane wave per node; lane owns 8 columns; the two wave halves process two
// edges concurrently (2 x 512B segments per load instruction); __shfl_xor combines.
__global__ __launch_bounds__(256) void aggregate_kernel(
    const unsigned short* __restrict__ xh, const unsigned short* __restrict__ x0b,
    const int* __restrict__ deg, const int* __restrict__ ell,
    unsigned short* __restrict__ h, int N)
{
    int node = blockIdx.x * 4 + (threadIdx.x >> 6);
    if (node >= N) return;
    const int lane = threadIdx.x & 63;
    const int half = lane >> 5;
    const int c    = (lane & 31) * 8;   // 8-column base

    const int dg = deg[node];
    const int ec = min(dg, ELL_W);
    const int* __restrict__ lst = ell + node * ELL_W;

    // hoisted epilogue operands: latency hides under the gather loop
    const float dscale = 0.9f / (float)max(dg, 1);
    const u16x8 xv = *(const u16x8*)(x0b + (size_t)node * DIM + c);

    float a[8];
    #pragma unroll
    for (int j = 0; j < 8; j++) a[j] = 0.f;

    int e = 0;
    for (; e + 4 <= ec; e += 4) {             // 4 edges per iter (2 per half)
        int s0 = lst[e + half];
        int s1 = lst[e + 2 + half];
        u16x8 v0 = *(const u16x8*)(xh + (size_t)s0 * DIM + c);
        u16x8 v1 = *(const u16x8*)(xh + (size_t)s1 * DIM + c);
        #pragma unroll
        for (int j = 0; j < 8; j++) a[j] += bf16_to_f32(v0[j]) + bf16_to_f32(v1[j]);
    }
    if (e + 2 <= ec) {                        // 2-edge remainder
        int s0 = lst[e + half];
        u16x8 v0 = *(const u16x8*)(xh + (size_t)s0 * DIM + c);
        #pragma unroll
        for (int j = 0; j < 8; j++) a[j] += bf16_to_f32(v0[j]);
        e += 2;
    }
    if (e < ec && half == 0) {                // odd tail: lo half only
        int s0 = lst[e];
        u16x8 v0 = *(const u16x8*)(xh + (size_t)s0 * DIM + c);
        #pragma unroll
        for (int j = 0; j < 8; j++) a[j] += bf16_to_f32(v0[j]);
    }

    // combine halves (all lanes participate)
    #pragma unroll
    for (int j = 0; j < 8; j++) a[j] += __shfl_xor(a[j], 32);

    if (half == 0) {
        u16x8 o;
        #pragma unroll
        for (int j = 0; j < 8; j++)
            o[j] = f32_to_bf16(0.1f * bf16_to_f32(xv[j]) + dscale * a[j]);
        *(u16x8*)(h + (size_t)node * DIM + c) = o;
    }
}

// ---------------- LDS-staged MFMA GEMM: out = relu(h @ W), pure bf16 ----------------
// v4: triple-buffered staging + COUNTED vmcnt (T4). Stage batch ks+2 each iter;
// per iter a single raw s_barrier preceded by s_waitcnt vmcnt(4): the oldest batch
// (4 loads/thread) is complete, the newest stays in flight across the barrier
// (never drain to 0 in the main loop). Addressing/swizzle identical to the
// r1-verified path (sg source pre-swizzle, q^xr read).
// Safety: writes at iter k target buf[(k+2)%3] == buffer read at iter k-1; every
// wave's iter-(k-1) ds_reads are lgkm-consumed before it reaches barrier k, and
// stores at iter k are issued only after barrier k => no overwrite race.
template <bool LAST>
__global__ __launch_bounds__(256) void gemm_kernel(
    const unsigned short* __restrict__ h, const unsigned short* __restrict__ Wt,
    float* __restrict__ out_f32, unsigned short* __restrict__ out_bf16, int N)
{
    __shared__ unsigned short As[3][128 * 32];  // 3 x 8 KB
    __shared__ unsigned short Bs[3][128 * 32];  // 3 x 8 KB

    const int t    = threadIdx.x;
    const int w    = t >> 6;
    const int lane = t & 63;
    const int lm   = lane & 15;
    const int q    = lane >> 4;
    const int wm   = w >> 1, wn = w & 1;
    const int m0   = blockIdx.x * 128;
    const int n0   = blockIdx.y * 128;

    const int sr = t >> 2;
    const int sg = ((t & 3) ^ ((t >> 3) & 3)) * 8;   // swizzled source col offset
    const int xr = (lm >> 1) & 3;                    // read-side swizzle term

    f32x4 acc[4][4];
    #pragma unroll
    for (int mi = 0; mi < 4; mi++)
        #pragma unroll
        for (int ni = 0; ni < 4; ni++)
            acc[mi][ni] = (f32x4){0.f, 0.f, 0.f, 0.f};

    // one staging batch = 4 load_lds16 per thread (A/B x 2 halves)
    auto stage = [&](int kb, int buf) {
        #pragma unroll
        for (int half = 0; half < 2; half++) {
            int r = half * 64 + sr;
            int ldso = (half * 256 + t) * 8;
            load_lds16(h  + (size_t)(m0 + r) * DIM + kb + sg, &As[buf][ldso]);
            load_lds16(Wt + (size_t)(n0 + r) * DIM + kb + sg, &Bs[buf][ldso]);
        }
    };

    stage(0, 0);     // batch 0
    stage(32, 1);    // batch 1

    #pragma unroll
    for (int ks = 0; ks < 8; ks++) {
        const int p = ks % 3;
        // oldest outstanding batch (the one feeding buf p) must be complete;
        // newest (4 loads/thread) may remain in flight across the barrier.
        if (ks < 7) asm volatile("s_waitcnt vmcnt(4)" ::: "memory");
        else        asm volatile("s_waitcnt vmcnt(0)" ::: "memory");
        __builtin_amdgcn_s_barrier();

        short8 a[4];
        #pragma unroll
        for (int mi = 0; mi < 4; mi++) {
            int row = wm * 64 + mi * 16 + lm;
            a[mi] = *(const short8*)&As[p][row * 32 + (q ^ xr) * 8];
        }

        if (ks < 6) stage((ks + 2) * 32, (ks + 2) % 3);   // batch ks+2

        #pragma unroll
        for (int ni = 0; ni < 4; ni++) {
            int row = wn * 64 + ni * 16 + lm;
            short8 b = *(const short8*)&Bs[p][row * 32 + (q ^ xr) * 8];
            #pragma unroll
            for (int mi = 0; mi < 4; mi++)
                acc[mi][ni] = __builtin_amdgcn_mfma_f32_16x16x32_bf16(a[mi], b, acc[mi][ni], 0, 0, 0);
        }
    }

    #pragma unroll
    for (int mi = 0; mi < 4; mi++) {
        const int rowb = m0 + wm * 64 + mi * 16 + q * 4;
        #pragma unroll
        for (int ni = 0; ni < 4; ni++) {
            const int col = n0 + wn * 64 + ni * 16 + lm;
            #pragma unroll
            for (int r = 0; r < 4; r++) {
                int row = rowb + r;
                if (row < N) {
                    float v = fmaxf(acc[mi][ni][r], 0.0f);
                    if (LAST) out_f32[(size_t)row * DIM + col] = v;
                    else      out_bf16[(size_t)row * DIM + col] = f32_to_bf16(v);
                }
            }
        }
    }
}

extern "C" void kernel_launch(void* const* d_in, const int* in_sizes, int n_in,
                              void* d_out, int out_size, void* d_ws, size_t ws_size,
                              hipStream_t stream) {
    const float* x0  = (const float*)d_in[0];
    const int*   ei  = (const int*)d_in[1];
    const float* W   = (const float*)d_in[2];
    float*       out = (float*)d_out;

    const int N = in_sizes[0] / DIM;
    const int E = in_sizes[1] / 2;
    const int N_pad = (N + 127) & ~127;
    const int* src = ei;
    const int* dst = ei + E;

    char* ws = (char*)d_ws;
    size_t off = 0;
    auto alloc = [&](size_t bytes) { char* p = ws + off; off += (bytes + 15) & ~size_t(15); return p; };
    unsigned short* h       = (unsigned short*)alloc((size_t)N_pad * DIM * 2);
    unsigned short* act     = (unsigned short*)alloc((size_t)N_pad * DIM * 2);
    unsigned short* x0b     = (unsigned short*)alloc((size_t)N_pad * DIM * 2);
    unsigned short* Wt      = (unsigned short*)alloc((size_t)DIM * DIM * 2);
    int*   cursor   = (int*)  alloc((size_t)N * 4);          // ends as in-degree
    int*   ell      = (int*)  alloc((size_t)N * ELL_W * 4);  // 6.4 MB slot table

    // ---- ELL build + W/x0 prep: 2 dispatches (was 6 + memset) ----
    const int nbE = (E + 255) / 256;
    const int n4 = N * DIM / 4;
    hipMemsetAsync(cursor, 0, (size_t)N * 4, stream);
    fillprep_kernel<<<nbE + DIM + (n4 + 255) / 256, 256, 0, stream>>>(
        src, dst, E, cursor, ell, W, Wt, x0, x0b, n4, nbE);

    // ---- 5 GCN layers (layer 0 gathers from x0b; then act) ----
    dim3 ggrid(N_pad / 128, 2);
    for (int layer = 0; layer < 5; layer++) {
        const unsigned short* gsrc = (layer == 0) ? x0b : act;
        aggregate_kernel<<<(N + 3) / 4, 256, 0, stream>>>(gsrc, x0b, cursor, ell, h, N);
        if (layer == 4)
            gemm_kernel<true><<<ggrid, 256, 0, stream>>>(h, Wt, out, nullptr, N);
        else
            gemm_kernel<false><<<ggrid, 256, 0, stream>>>(h, Wt, nullptr, act, N);
    }
}